// Round 1
// baseline (555.501 us; speedup 1.0000x reference)
//
#include <hip/hip_runtime.h>
#include <hip/hip_bf16.h>

#define N_NODES 50000
#define N_EDGES 800000
#define HDIM    128
#define N_RELS  24

// Each relation's edge list padded to a multiple of 64:
// max padded total = 800000 + 24*63 = 801512 -> 12524 tiles -> 801536 slots
#define MAX_TILES  12524
#define SORTED_CAP (MAX_TILES * 64)

typedef __attribute__((ext_vector_type(8))) short bf16x8;
typedef __attribute__((ext_vector_type(4))) float f32x4;

// meta layout (ints): [0..23] hist, [32..55] cursor, [64..88] base(25), [96..120] tilebase(25)
// tilebase[24] (= meta[120]) is total tile count.

__global__ void k_init(const float* __restrict__ h,
                       const float* __restrict__ W,
                       const float* __restrict__ Wl,
                       __hip_bfloat16* __restrict__ hb,
                       __hip_bfloat16* __restrict__ Wbt,
                       __hip_bfloat16* __restrict__ Wlbt,
                       float* __restrict__ agg,
                       float* __restrict__ deg,
                       int* __restrict__ meta,
                       int* __restrict__ sorted)
{
    int stride = gridDim.x * blockDim.x;
    int tid = blockIdx.x * blockDim.x + threadIdx.x;

    for (int i = tid; i < N_NODES * HDIM; i += stride) {
        hb[i] = __float2bfloat16(h[i]);
        agg[i] = 0.0f;
    }
    // Wbt[r][e][k] = W[r][k][e]  (transposed so MFMA B-frag reads are contiguous in k)
    for (int i = tid; i < N_RELS * HDIM * HDIM; i += stride) {
        int r = i >> 14;
        int rem = i & 16383;
        int e = rem >> 7;
        int k = rem & 127;
        Wbt[i] = __float2bfloat16(W[(r << 14) + (k << 7) + e]);
    }
    for (int i = tid; i < HDIM * HDIM; i += stride) {
        int e = i >> 7, k = i & 127;
        Wlbt[i] = __float2bfloat16(Wl[(k << 7) + e]);
    }
    for (int i = tid; i < N_NODES; i += stride) deg[i] = 0.0f;
    for (int i = tid; i < 64; i += stride) meta[i] = 0;       // hist + cursor
    for (int i = tid; i < SORTED_CAP; i += stride) sorted[i] = -1;
}

__global__ void k_hist(const int* __restrict__ rel,
                       const int* __restrict__ dst,
                       int* __restrict__ meta,
                       float* __restrict__ deg)
{
    __shared__ int lh[N_RELS];
    if (threadIdx.x < N_RELS) lh[threadIdx.x] = 0;
    __syncthreads();
    int e = blockIdx.x * blockDim.x + threadIdx.x;
    if (e < N_EDGES) {
        atomicAdd(&lh[rel[e]], 1);
        atomicAdd(&deg[dst[e]], 1.0f);
    }
    __syncthreads();
    if (threadIdx.x < N_RELS) atomicAdd(&meta[threadIdx.x], lh[threadIdx.x]);
}

__global__ void k_scan(int* __restrict__ meta)
{
    if (blockIdx.x == 0 && threadIdx.x == 0) {
        int run = 0;
        for (int r = 0; r < N_RELS; ++r) {
            meta[64 + r] = run;          // base (element offset in sorted[])
            meta[96 + r] = run >> 6;     // tile base
            int cnt = meta[r];
            run += ((cnt + 63) >> 6) << 6;
        }
        meta[64 + N_RELS] = run;
        meta[96 + N_RELS] = run >> 6;    // total tiles
    }
}

__global__ void k_scatter(const int* __restrict__ rel,
                          int* __restrict__ meta,
                          int* __restrict__ sorted)
{
    __shared__ int lh[N_RELS], lb[N_RELS];
    if (threadIdx.x < N_RELS) lh[threadIdx.x] = 0;
    __syncthreads();
    int e = blockIdx.x * blockDim.x + threadIdx.x;
    int r = 0, my = 0;
    bool valid = (e < N_EDGES);
    if (valid) {
        r = rel[e];
        my = atomicAdd(&lh[r], 1);
    }
    __syncthreads();
    if (threadIdx.x < N_RELS)
        lb[threadIdx.x] = atomicAdd(&meta[32 + threadIdx.x], lh[threadIdx.x]);
    __syncthreads();
    if (valid) sorted[meta[64 + r] + lb[r] + my] = e;
}

// Edge message GEMM: one block = 64 edges (same relation) x 128 output dims.
// A = gathered h rows (64x128 bf16, LDS, XOR-swizzled), B = W[rel]^T (128x128 bf16, LDS).
// C scattered via f32 atomics into agg[dst].
__global__ __launch_bounds__(256) void k_edge(
    const __hip_bfloat16* __restrict__ hb,
    const __hip_bfloat16* __restrict__ Wbt,
    const int* __restrict__ src,
    const int* __restrict__ dst,
    const int* __restrict__ meta,
    const int* __restrict__ sorted,
    float* __restrict__ agg)
{
    __shared__ __align__(16) unsigned char As[64 * 256];
    __shared__ __align__(16) unsigned char Ws[128 * 256];
    __shared__ int dstL[64];

    int b = blockIdx.x;
    if (b >= meta[96 + N_RELS]) return;
    int r = 0;
    while (b >= meta[96 + r + 1]) ++r;

    int t = threadIdx.x;
    if (t < 64) {
        int eid = sorted[(b << 6) + t];
        dstL[t] = (eid >= 0) ? dst[eid] : -1;
    }
    {   // gather A rows: 4 threads per edge, 64B each
        int i = t >> 2, q = t & 3;
        int eid = sorted[(b << 6) + i];
        if (eid >= 0) {
            int s = src[eid];
            const uint4* g = (const uint4*)((const char*)hb + (size_t)s * 256);
            unsigned sw = (i & 7) << 4;
            #pragma unroll
            for (int j = 0; j < 4; ++j) {
                int cb = (q << 6) + (j << 4);
                *(uint4*)(As + i * 256 + (cb ^ sw)) = g[cb >> 4];
            }
        }
    }
    {   // stage W[r]^T: 2 threads per row, 128B each
        int row = t >> 1, half = t & 1;
        const uint4* g = (const uint4*)((const char*)Wbt + (size_t)r * 32768 + row * 256);
        unsigned sw = (row & 7) << 4;
        #pragma unroll
        for (int j = 0; j < 8; ++j) {
            int cb = (half << 7) + (j << 4);
            *(uint4*)(Ws + row * 256 + (cb ^ sw)) = g[cb >> 4];
        }
    }
    __syncthreads();

    int lane = t & 63, wave = t >> 6;
    int l15 = lane & 15, l4 = lane >> 4;
    f32x4 acc[8];
    #pragma unroll
    for (int c = 0; c < 8; ++c) acc[c] = (f32x4)0.0f;

    #pragma unroll
    for (int kk = 0; kk < 4; ++kk) {
        int kb = (kk << 6) + (l4 << 4);            // byte offset of this lane's 8 bf16 in k
        int arow = (wave << 4) + l15;
        bf16x8 a = *(const bf16x8*)(As + arow * 256 + (kb ^ ((arow & 7) << 4)));
        #pragma unroll
        for (int c = 0; c < 8; ++c) {
            int brow = (c << 4) + l15;
            bf16x8 bb = *(const bf16x8*)(Ws + brow * 256 + (kb ^ ((brow & 7) << 4)));
            acc[c] = __builtin_amdgcn_mfma_f32_16x16x32_bf16(a, bb, acc[c], 0, 0, 0);
        }
    }

    #pragma unroll
    for (int c = 0; c < 8; ++c) {
        #pragma unroll
        for (int i = 0; i < 4; ++i) {
            int m = (wave << 4) + (l4 << 2) + i;   // edge slot in tile
            int d = dstL[m];
            if (d >= 0)
                atomicAdd(&agg[d * 128 + (c << 4) + l15], acc[c][i]);
        }
    }
}

// Self-loop GEMM fused with mean-division, bias, ReLU. In-place on agg (= d_out).
__global__ __launch_bounds__(256) void k_self(
    const __hip_bfloat16* __restrict__ hb,
    const __hip_bfloat16* __restrict__ Wlbt,
    const float* __restrict__ bias,
    const float* __restrict__ deg,
    float* __restrict__ agg)
{
    __shared__ __align__(16) unsigned char As[64 * 256];
    __shared__ __align__(16) unsigned char Ws[128 * 256];

    int b = blockIdx.x, t = threadIdx.x;
    int n0 = b << 6;
    {
        int i = t >> 2, q = t & 3;
        int v = n0 + i;
        if (v < N_NODES) {
            const uint4* g = (const uint4*)((const char*)hb + (size_t)v * 256);
            unsigned sw = (i & 7) << 4;
            #pragma unroll
            for (int j = 0; j < 4; ++j) {
                int cb = (q << 6) + (j << 4);
                *(uint4*)(As + i * 256 + (cb ^ sw)) = g[cb >> 4];
            }
        }
    }
    {
        int row = t >> 1, half = t & 1;
        const uint4* g = (const uint4*)((const char*)Wlbt + row * 256);
        unsigned sw = (row & 7) << 4;
        #pragma unroll
        for (int j = 0; j < 8; ++j) {
            int cb = (half << 7) + (j << 4);
            *(uint4*)(Ws + row * 256 + (cb ^ sw)) = g[cb >> 4];
        }
    }
    __syncthreads();

    int lane = t & 63, wave = t >> 6;
    int l15 = lane & 15, l4 = lane >> 4;
    f32x4 acc[8];
    #pragma unroll
    for (int c = 0; c < 8; ++c) acc[c] = (f32x4)0.0f;

    #pragma unroll
    for (int kk = 0; kk < 4; ++kk) {
        int kb = (kk << 6) + (l4 << 4);
        int arow = (wave << 4) + l15;
        bf16x8 a = *(const bf16x8*)(As + arow * 256 + (kb ^ ((arow & 7) << 4)));
        #pragma unroll
        for (int c = 0; c < 8; ++c) {
            int brow = (c << 4) + l15;
            bf16x8 bb = *(const bf16x8*)(Ws + brow * 256 + (kb ^ ((brow & 7) << 4)));
            acc[c] = __builtin_amdgcn_mfma_f32_16x16x32_bf16(a, bb, acc[c], 0, 0, 0);
        }
    }

    #pragma unroll
    for (int c = 0; c < 8; ++c) {
        #pragma unroll
        for (int i = 0; i < 4; ++i) {
            int m = (wave << 4) + (l4 << 2) + i;
            int v = n0 + m;
            if (v < N_NODES) {
                int col = (c << 4) + l15;
                float dv = deg[v];
                float inv = 1.0f / fmaxf(dv, 1.0f);
                float val = acc[c][i] + agg[v * 128 + col] * inv + bias[col];
                agg[v * 128 + col] = fmaxf(val, 0.0f);
            }
        }
    }
}

extern "C" void kernel_launch(void* const* d_in, const int* in_sizes, int n_in,
                              void* d_out, int out_size, void* d_ws, size_t ws_size,
                              hipStream_t stream)
{
    (void)in_sizes; (void)n_in; (void)out_size; (void)ws_size;

    const float* h    = (const float*)d_in[0];
    const float* W    = (const float*)d_in[1];
    const float* Wl   = (const float*)d_in[2];
    const float* bias = (const float*)d_in[3];
    const int*   src  = (const int*)d_in[4];
    const int*   dst  = (const int*)d_in[5];
    const int*   rel  = (const int*)d_in[6];
    float* out = (float*)d_out;

    char* ws = (char*)d_ws;
    size_t off = 0;
    auto take = [&](size_t bytes) -> char* {
        char* p = ws + off;
        off += (bytes + 255) & ~(size_t)255;
        return p;
    };
    __hip_bfloat16* hb   = (__hip_bfloat16*)take((size_t)N_NODES * HDIM * 2);
    __hip_bfloat16* Wbt  = (__hip_bfloat16*)take((size_t)N_RELS * HDIM * HDIM * 2);
    __hip_bfloat16* Wlbt = (__hip_bfloat16*)take((size_t)HDIM * HDIM * 2);
    float* deg  = (float*)take((size_t)N_NODES * 4);
    int*   meta = (int*)take(1024);
    int*   sorted = (int*)take((size_t)SORTED_CAP * 4);
    float* agg = out;   // edge aggregation lives in d_out; epilogue rewrites in place

    k_init<<<2048, 256, 0, stream>>>(h, W, Wl, hb, Wbt, Wlbt, agg, deg, meta, sorted);
    k_hist<<<(N_EDGES + 255) / 256, 256, 0, stream>>>(rel, dst, meta, deg);
    k_scan<<<1, 64, 0, stream>>>(meta);
    k_scatter<<<(N_EDGES + 255) / 256, 256, 0, stream>>>(rel, meta, sorted);
    k_edge<<<MAX_TILES, 256, 0, stream>>>(hb, Wbt, src, dst, meta, sorted, agg);
    k_self<<<(N_NODES + 63) / 64, 256, 0, stream>>>(hb, Wlbt, bias, deg, agg);
}

// Round 2
// 391.623 us; speedup vs baseline: 1.4185x; 1.4185x over previous
//
#include <hip/hip_runtime.h>
#include <hip/hip_bf16.h>

#define N_NODES 50000
#define N_EDGES 800000
#define HDIM    128
#define N_RELS  24

// rel-padded tile capacity: 800000 + 24*63 -> 12524 tiles of 64
#define MAX_TILES  12524
#define SORTED_CAP (MAX_TILES * 64)
#define NSCAN_BLK  196          // ceil(50000/256)

typedef __attribute__((ext_vector_type(8))) short bf16x8;
typedef __attribute__((ext_vector_type(4))) float f32x4;

static __device__ __forceinline__ float bfbits2f(unsigned u) {
    return __uint_as_float(u << 16);            // bf16 -> f32 exact
}
static __device__ __forceinline__ unsigned f2bfbits(float x) {
    union { __hip_bfloat16 b; unsigned short u; } cv;
    cv.b = __float2bfloat16(x);                 // round-to-nearest
    return (unsigned)cv.u;
}

// ---------------- shared setup kernels ----------------

__global__ void k_convert(const float* __restrict__ h,
                          const float* __restrict__ W,
                          const float* __restrict__ Wl,
                          __hip_bfloat16* __restrict__ hb,
                          __hip_bfloat16* __restrict__ Wbt,
                          __hip_bfloat16* __restrict__ Wlbt,
                          int* __restrict__ degi,
                          int* __restrict__ meta,
                          float* __restrict__ aggz,   // d_out zero (path B only)
                          int zero_agg)
{
    int stride = gridDim.x * blockDim.x;
    int tid = blockIdx.x * blockDim.x + threadIdx.x;

    for (int i = tid; i < N_NODES * HDIM; i += stride)
        hb[i] = __float2bfloat16(h[i]);
    // Wbt[r][e][k] = W[r][k][e]
    for (int i = tid; i < N_RELS * HDIM * HDIM; i += stride) {
        int r = i >> 14, rem = i & 16383;
        int e = rem >> 7, k = rem & 127;
        Wbt[i] = __float2bfloat16(W[(r << 14) + (k << 7) + e]);
    }
    for (int i = tid; i < HDIM * HDIM; i += stride) {
        int e = i >> 7, k = i & 127;
        Wlbt[i] = __float2bfloat16(Wl[(k << 7) + e]);
    }
    for (int i = tid; i < N_NODES; i += stride) degi[i] = 0;
    for (int i = tid; i < 64; i += stride) meta[i] = 0;
    if (zero_agg) {
        for (int i = tid; i < N_NODES * HDIM; i += stride) aggz[i] = 0.0f;
    }
}

__global__ void k_hist(const int* __restrict__ rel,
                       const int* __restrict__ dst,
                       int* __restrict__ meta,
                       int* __restrict__ degi)
{
    __shared__ int lh[N_RELS];
    if (threadIdx.x < N_RELS) lh[threadIdx.x] = 0;
    __syncthreads();
    int e = blockIdx.x * blockDim.x + threadIdx.x;
    if (e < N_EDGES) {
        atomicAdd(&lh[rel[e]], 1);
        atomicAdd(&degi[dst[e]], 1);
    }
    __syncthreads();
    if (threadIdx.x < N_RELS) atomicAdd(&meta[threadIdx.x], lh[threadIdx.x]);
}

__global__ void k_scan_rel(int* __restrict__ meta)
{
    if (blockIdx.x == 0 && threadIdx.x == 0) {
        int run = 0;
        for (int r = 0; r < N_RELS; ++r) {
            meta[64 + r] = run;          // element base in sorted[]
            meta[96 + r] = run >> 6;     // tile base
            int cnt = meta[r];
            run += ((cnt + 63) >> 6) << 6;
        }
        meta[64 + N_RELS] = run;
        meta[96 + N_RELS] = run >> 6;    // total tiles
    }
}

__global__ void k_scatter(const int* __restrict__ rel,
                          int* __restrict__ meta,
                          int* __restrict__ sorted)
{
    __shared__ int lh[N_RELS], lb[N_RELS];
    if (threadIdx.x < N_RELS) lh[threadIdx.x] = 0;
    __syncthreads();
    int e = blockIdx.x * blockDim.x + threadIdx.x;
    int r = 0, my = 0;
    bool valid = (e < N_EDGES);
    if (valid) {
        r = rel[e];
        my = atomicAdd(&lh[r], 1);
    }
    __syncthreads();
    if (threadIdx.x < N_RELS)
        lb[threadIdx.x] = atomicAdd(&meta[32 + threadIdx.x], lh[threadIdx.x]);
    __syncthreads();
    if (valid) sorted[meta[64 + r] + lb[r] + my] = e;
}

// ---------------- dst exclusive scan (path A) ----------------

__global__ void k_bsum(const int* __restrict__ degi, int* __restrict__ bsum)
{
    int i = blockIdx.x * 256 + threadIdx.x;
    int v = (i < N_NODES) ? degi[i] : 0;
    #pragma unroll
    for (int d = 32; d > 0; d >>= 1) v += __shfl_down(v, d);
    __shared__ int ws4[4];
    int lane = threadIdx.x & 63, wv = threadIdx.x >> 6;
    if (lane == 0) ws4[wv] = v;
    __syncthreads();
    if (threadIdx.x == 0)
        bsum[blockIdx.x] = ws4[0] + ws4[1] + ws4[2] + ws4[3];
}

__global__ void k_bscan(const int* __restrict__ bsum, int* __restrict__ boff,
                        int* __restrict__ seg)
{
    if (threadIdx.x == 0 && blockIdx.x == 0) {
        int run = 0;
        for (int b = 0; b < NSCAN_BLK; ++b) { boff[b] = run; run += bsum[b]; }
        seg[N_NODES] = run;   // == N_EDGES
    }
}

__global__ void k_seg(const int* __restrict__ degi, const int* __restrict__ boff,
                      int* __restrict__ seg, int* __restrict__ cursor)
{
    int i = blockIdx.x * 256 + threadIdx.x;
    int lane = threadIdx.x & 63, wv = threadIdx.x >> 6;
    int v = (i < N_NODES) ? degi[i] : 0;
    int x = v;
    #pragma unroll
    for (int d = 1; d < 64; d <<= 1) {
        int y = __shfl_up(x, d);
        if (lane >= d) x += y;
    }
    __shared__ int wpart[4];
    if (lane == 63) wpart[wv] = x;
    __syncthreads();
    int add = 0;
    for (int w = 0; w < wv; ++w) add += wpart[w];
    int s = boff[blockIdx.x] + add + x - v;   // exclusive
    if (i < N_NODES) { seg[i] = s; cursor[i] = s; }
}

// ---------------- path A: msg-writing edge GEMM ----------------

__global__ __launch_bounds__(256) void k_edgeA(
    const __hip_bfloat16* __restrict__ hb,
    const __hip_bfloat16* __restrict__ Wbt,
    const int* __restrict__ src,
    const int* __restrict__ dst,
    const int* __restrict__ meta,
    const int* __restrict__ sorted,
    int* __restrict__ cursor,
    __hip_bfloat16* __restrict__ msg)
{
    __shared__ __align__(16) unsigned char smem[49152];  // As 16K | Ws 32K, reused for C f32
    __shared__ int slotL[64];

    int b = blockIdx.x;
    if (b >= meta[96 + N_RELS]) return;
    int r = 0;
    while (b >= meta[96 + r + 1]) ++r;
    int cnt = meta[r];
    int lbase = (b - meta[96 + r]) << 6;
    int t = threadIdx.x;

    if (t < 64) {
        if (lbase + t < cnt) {
            int eid = sorted[(b << 6) + t];
            slotL[t] = atomicAdd(&cursor[dst[eid]], 1);
        } else slotL[t] = -1;
    }
    {   // gather A rows: 4 threads per edge, 64B each
        int i = t >> 2, q = t & 3;
        if (lbase + i < cnt) {
            int eid = sorted[(b << 6) + i];
            int s = src[eid];
            const uint4* g = (const uint4*)((const char*)hb + (size_t)s * 256);
            unsigned sw = (i & 7) << 4;
            #pragma unroll
            for (int j = 0; j < 4; ++j) {
                int cb = (q << 6) + (j << 4);
                *(uint4*)(smem + i * 256 + (cb ^ sw)) = g[cb >> 4];
            }
        }
    }
    {   // stage W[r]^T: 2 threads per row, 128B each
        unsigned char* Ws = smem + 16384;
        int row = t >> 1, half = t & 1;
        const uint4* g = (const uint4*)((const char*)Wbt + (size_t)r * 32768 + row * 256);
        unsigned sw = (row & 7) << 4;
        #pragma unroll
        for (int j = 0; j < 8; ++j) {
            int cb = (half << 7) + (j << 4);
            *(uint4*)(Ws + row * 256 + (cb ^ sw)) = g[cb >> 4];
        }
    }
    __syncthreads();

    int lane = t & 63, wave = t >> 6;
    int l15 = lane & 15, l4 = lane >> 4;
    f32x4 acc[8];
    #pragma unroll
    for (int c = 0; c < 8; ++c) acc[c] = (f32x4)0.0f;

    #pragma unroll
    for (int kk = 0; kk < 4; ++kk) {
        int kb = (kk << 6) + (l4 << 4);
        int arow = (wave << 4) + l15;
        bf16x8 a = *(const bf16x8*)(smem + arow * 256 + (kb ^ ((arow & 7) << 4)));
        #pragma unroll
        for (int c = 0; c < 8; ++c) {
            int brow = (c << 4) + l15;
            bf16x8 bb = *(const bf16x8*)(smem + 16384 + brow * 256 + (kb ^ ((brow & 7) << 4)));
            acc[c] = __builtin_amdgcn_mfma_f32_16x16x32_bf16(a, bb, acc[c], 0, 0, 0);
        }
    }
    __syncthreads();

    // C tile -> LDS f32 [64][132]
    float* C = (float*)smem;
    #pragma unroll
    for (int c = 0; c < 8; ++c) {
        #pragma unroll
        for (int i = 0; i < 4; ++i) {
            int m = (wave << 4) + (l4 << 2) + i;
            C[m * 132 + (c << 4) + l15] = acc[c][i];
        }
    }
    __syncthreads();

    // readout: 4 threads per edge, each converts 32 f32 -> 32 bf16 and writes 64B
    {
        int i = t >> 2, q = t & 3;
        if (lbase + i < cnt) {
            int slot = slotL[i];
            const f32x4* rp = (const f32x4*)(C + i * 132 + q * 32);
            unsigned u[16];
            #pragma unroll
            for (int jj = 0; jj < 8; ++jj) {
                f32x4 x = rp[jj];
                u[2 * jj]     = f2bfbits(x[0]) | (f2bfbits(x[1]) << 16);
                u[2 * jj + 1] = f2bfbits(x[2]) | (f2bfbits(x[3]) << 16);
            }
            uint4* dp = (uint4*)((char*)msg + (size_t)slot * 256 + q * 64);
            dp[0] = uint4{u[0], u[1], u[2], u[3]};
            dp[1] = uint4{u[4], u[5], u[6], u[7]};
            dp[2] = uint4{u[8], u[9], u[10], u[11]};
            dp[3] = uint4{u[12], u[13], u[14], u[15]};
        }
    }
}

// segment mean: one wave per node, coalesced reads of its contiguous msg run
__global__ __launch_bounds__(256) void k_agg(
    const __hip_bfloat16* __restrict__ msg,
    const int* __restrict__ seg,
    __hip_bfloat16* __restrict__ aggB)
{
    int wv = threadIdx.x >> 6, lane = threadIdx.x & 63;
    int n = blockIdx.x * 4 + wv;
    if (n >= N_NODES) return;
    int s0 = seg[n], s1 = seg[n + 1];
    int deg = s1 - s0;
    int l4 = lane >> 4, l15 = lane & 15;

    float acc[8] = {0, 0, 0, 0, 0, 0, 0, 0};
    const char* base = (const char*)msg + (size_t)s0 * 256;
    int nit = (deg + 3) >> 2;
    for (int it = 0; it < nit; ++it) {
        if (it * 4 + l4 < deg) {
            uint4 v = *(const uint4*)(base + (size_t)it * 1024 + lane * 16);
            acc[0] += bfbits2f(v.x & 0xffff); acc[1] += bfbits2f(v.x >> 16);
            acc[2] += bfbits2f(v.y & 0xffff); acc[3] += bfbits2f(v.y >> 16);
            acc[4] += bfbits2f(v.z & 0xffff); acc[5] += bfbits2f(v.z >> 16);
            acc[6] += bfbits2f(v.w & 0xffff); acc[7] += bfbits2f(v.w >> 16);
        }
    }
    #pragma unroll
    for (int k = 0; k < 8; ++k) {
        acc[k] += __shfl_xor(acc[k], 16);
        acc[k] += __shfl_xor(acc[k], 32);
    }
    if (l4 == 0) {
        float inv = 1.0f / fmaxf((float)deg, 1.0f);
        unsigned u[4];
        #pragma unroll
        for (int p = 0; p < 4; ++p)
            u[p] = f2bfbits(acc[2 * p] * inv) | (f2bfbits(acc[2 * p + 1] * inv) << 16);
        *(uint4*)((char*)aggB + (size_t)n * 256 + l15 * 16) = uint4{u[0], u[1], u[2], u[3]};
    }
}

// self-loop GEMM + meaned-agg + bias + relu  (path A epilogue)
__global__ __launch_bounds__(256) void k_selfA(
    const __hip_bfloat16* __restrict__ hb,
    const __hip_bfloat16* __restrict__ Wlbt,
    const float* __restrict__ bias,
    const __hip_bfloat16* __restrict__ aggB,
    float* __restrict__ out)
{
    __shared__ __align__(16) unsigned char As[64 * 256];
    __shared__ __align__(16) unsigned char Ws[128 * 256];

    int b = blockIdx.x, t = threadIdx.x;
    int n0 = b << 6;
    {
        int i = t >> 2, q = t & 3;
        int v = n0 + i;
        if (v < N_NODES) {
            const uint4* g = (const uint4*)((const char*)hb + (size_t)v * 256);
            unsigned sw = (i & 7) << 4;
            #pragma unroll
            for (int j = 0; j < 4; ++j) {
                int cb = (q << 6) + (j << 4);
                *(uint4*)(As + i * 256 + (cb ^ sw)) = g[cb >> 4];
            }
        }
    }
    {
        int row = t >> 1, half = t & 1;
        const uint4* g = (const uint4*)((const char*)Wlbt + row * 256);
        unsigned sw = (row & 7) << 4;
        #pragma unroll
        for (int j = 0; j < 8; ++j) {
            int cb = (half << 7) + (j << 4);
            *(uint4*)(Ws + row * 256 + (cb ^ sw)) = g[cb >> 4];
        }
    }
    __syncthreads();

    int lane = t & 63, wave = t >> 6;
    int l15 = lane & 15, l4 = lane >> 4;
    f32x4 acc[8];
    #pragma unroll
    for (int c = 0; c < 8; ++c) acc[c] = (f32x4)0.0f;

    #pragma unroll
    for (int kk = 0; kk < 4; ++kk) {
        int kb = (kk << 6) + (l4 << 4);
        int arow = (wave << 4) + l15;
        bf16x8 a = *(const bf16x8*)(As + arow * 256 + (kb ^ ((arow & 7) << 4)));
        #pragma unroll
        for (int c = 0; c < 8; ++c) {
            int brow = (c << 4) + l15;
            bf16x8 bb = *(const bf16x8*)(Ws + brow * 256 + (kb ^ ((brow & 7) << 4)));
            acc[c] = __builtin_amdgcn_mfma_f32_16x16x32_bf16(a, bb, acc[c], 0, 0, 0);
        }
    }

    #pragma unroll
    for (int c = 0; c < 8; ++c) {
        #pragma unroll
        for (int i = 0; i < 4; ++i) {
            int m = (wave << 4) + (l4 << 2) + i;
            int v = n0 + m;
            if (v < N_NODES) {
                int col = (c << 4) + l15;
                float ag = bfbits2f(((const unsigned short*)aggB)[v * 128 + col]);
                float val = acc[c][i] + ag + bias[col];
                out[v * 128 + col] = fmaxf(val, 0.0f);
            }
        }
    }
}

// ---------------- path B (fallback): verified round-1 atomic scheme ----------------

__global__ __launch_bounds__(256) void k_edgeB(
    const __hip_bfloat16* __restrict__ hb,
    const __hip_bfloat16* __restrict__ Wbt,
    const int* __restrict__ src,
    const int* __restrict__ dst,
    const int* __restrict__ meta,
    const int* __restrict__ sorted,
    float* __restrict__ agg)
{
    __shared__ __align__(16) unsigned char As[64 * 256];
    __shared__ __align__(16) unsigned char Ws[128 * 256];
    __shared__ int dstL[64];

    int b = blockIdx.x;
    if (b >= meta[96 + N_RELS]) return;
    int r = 0;
    while (b >= meta[96 + r + 1]) ++r;
    int cnt = meta[r];
    int lbase = (b - meta[96 + r]) << 6;
    int t = threadIdx.x;

    if (t < 64) {
        if (lbase + t < cnt) dstL[t] = dst[sorted[(b << 6) + t]];
        else dstL[t] = -1;
    }
    {
        int i = t >> 2, q = t & 3;
        if (lbase + i < cnt) {
            int s = src[sorted[(b << 6) + i]];
            const uint4* g = (const uint4*)((const char*)hb + (size_t)s * 256);
            unsigned sw = (i & 7) << 4;
            #pragma unroll
            for (int j = 0; j < 4; ++j) {
                int cb = (q << 6) + (j << 4);
                *(uint4*)(As + i * 256 + (cb ^ sw)) = g[cb >> 4];
            }
        }
    }
    {
        int row = t >> 1, half = t & 1;
        const uint4* g = (const uint4*)((const char*)Wbt + (size_t)r * 32768 + row * 256);
        unsigned sw = (row & 7) << 4;
        #pragma unroll
        for (int j = 0; j < 8; ++j) {
            int cb = (half << 7) + (j << 4);
            *(uint4*)(Ws + row * 256 + (cb ^ sw)) = g[cb >> 4];
        }
    }
    __syncthreads();

    int lane = t & 63, wave = t >> 6;
    int l15 = lane & 15, l4 = lane >> 4;
    f32x4 acc[8];
    #pragma unroll
    for (int c = 0; c < 8; ++c) acc[c] = (f32x4)0.0f;

    #pragma unroll
    for (int kk = 0; kk < 4; ++kk) {
        int kb = (kk << 6) + (l4 << 4);
        int arow = (wave << 4) + l15;
        bf16x8 a = *(const bf16x8*)(As + arow * 256 + (kb ^ ((arow & 7) << 4)));
        #pragma unroll
        for (int c = 0; c < 8; ++c) {
            int brow = (c << 4) + l15;
            bf16x8 bb = *(const bf16x8*)(Ws + brow * 256 + (kb ^ ((brow & 7) << 4)));
            acc[c] = __builtin_amdgcn_mfma_f32_16x16x32_bf16(a, bb, acc[c], 0, 0, 0);
        }
    }

    #pragma unroll
    for (int c = 0; c < 8; ++c) {
        #pragma unroll
        for (int i = 0; i < 4; ++i) {
            int m = (wave << 4) + (l4 << 2) + i;
            int d = dstL[m];
            if (d >= 0)
                atomicAdd(&agg[d * 128 + (c << 4) + l15], acc[c][i]);
        }
    }
}

__global__ __launch_bounds__(256) void k_selfB(
    const __hip_bfloat16* __restrict__ hb,
    const __hip_bfloat16* __restrict__ Wlbt,
    const float* __restrict__ bias,
    const int* __restrict__ degi,
    float* __restrict__ agg)
{
    __shared__ __align__(16) unsigned char As[64 * 256];
    __shared__ __align__(16) unsigned char Ws[128 * 256];

    int b = blockIdx.x, t = threadIdx.x;
    int n0 = b << 6;
    {
        int i = t >> 2, q = t & 3;
        int v = n0 + i;
        if (v < N_NODES) {
            const uint4* g = (const uint4*)((const char*)hb + (size_t)v * 256);
            unsigned sw = (i & 7) << 4;
            #pragma unroll
            for (int j = 0; j < 4; ++j) {
                int cb = (q << 6) + (j << 4);
                *(uint4*)(As + i * 256 + (cb ^ sw)) = g[cb >> 4];
            }
        }
    }
    {
        int row = t >> 1, half = t & 1;
        const uint4* g = (const uint4*)((const char*)Wlbt + row * 256);
        unsigned sw = (row & 7) << 4;
        #pragma unroll
        for (int j = 0; j < 8; ++j) {
            int cb = (half << 7) + (j << 4);
            *(uint4*)(Ws + row * 256 + (cb ^ sw)) = g[cb >> 4];
        }
    }
    __syncthreads();

    int lane = t & 63, wave = t >> 6;
    int l15 = lane & 15, l4 = lane >> 4;
    f32x4 acc[8];
    #pragma unroll
    for (int c = 0; c < 8; ++c) acc[c] = (f32x4)0.0f;

    #pragma unroll
    for (int kk = 0; kk < 4; ++kk) {
        int kb = (kk << 6) + (l4 << 4);
        int arow = (wave << 4) + l15;
        bf16x8 a = *(const bf16x8*)(As + arow * 256 + (kb ^ ((arow & 7) << 4)));
        #pragma unroll
        for (int c = 0; c < 8; ++c) {
            int brow = (c << 4) + l15;
            bf16x8 bb = *(const bf16x8*)(Ws + brow * 256 + (kb ^ ((brow & 7) << 4)));
            acc[c] = __builtin_amdgcn_mfma_f32_16x16x32_bf16(a, bb, acc[c], 0, 0, 0);
        }
    }

    #pragma unroll
    for (int c = 0; c < 8; ++c) {
        #pragma unroll
        for (int i = 0; i < 4; ++i) {
            int m = (wave << 4) + (l4 << 2) + i;
            int v = n0 + m;
            if (v < N_NODES) {
                int col = (c << 4) + l15;
                float inv = 1.0f / fmaxf((float)degi[v], 1.0f);
                float val = acc[c][i] + agg[v * 128 + col] * inv + bias[col];
                agg[v * 128 + col] = fmaxf(val, 0.0f);
            }
        }
    }
}

// ---------------- launch ----------------

extern "C" void kernel_launch(void* const* d_in, const int* in_sizes, int n_in,
                              void* d_out, int out_size, void* d_ws, size_t ws_size,
                              hipStream_t stream)
{
    (void)in_sizes; (void)n_in; (void)out_size;

    const float* h    = (const float*)d_in[0];
    const float* W    = (const float*)d_in[1];
    const float* Wl   = (const float*)d_in[2];
    const float* bias = (const float*)d_in[3];
    const int*   src  = (const int*)d_in[4];
    const int*   dst  = (const int*)d_in[5];
    const int*   rel  = (const int*)d_in[6];
    float* out = (float*)d_out;

    char* ws = (char*)d_ws;
    size_t off = 0;
    auto take = [&](size_t bytes) -> char* {
        char* p = ws + off;
        off += (bytes + 255) & ~(size_t)255;
        return p;
    };
    __hip_bfloat16* hb   = (__hip_bfloat16*)take((size_t)N_NODES * HDIM * 2);
    __hip_bfloat16* Wbt  = (__hip_bfloat16*)take((size_t)N_RELS * HDIM * HDIM * 2);
    __hip_bfloat16* Wlbt = (__hip_bfloat16*)take((size_t)HDIM * HDIM * 2);
    int*   degi   = (int*)take((size_t)N_NODES * 4);
    int*   meta   = (int*)take(1024);
    int*   sorted = (int*)take((size_t)SORTED_CAP * 4);
    int*   seg    = (int*)take((size_t)(N_NODES + 1) * 4);
    int*   cursor = (int*)take((size_t)N_NODES * 4);
    int*   bsum   = (int*)take((size_t)NSCAN_BLK * 4);
    int*   boff   = (int*)take((size_t)NSCAN_BLK * 4);
    size_t small_need = off;
    __hip_bfloat16* msg  = (__hip_bfloat16*)take((size_t)N_EDGES * HDIM * 2);
    __hip_bfloat16* aggB = (__hip_bfloat16*)take((size_t)N_NODES * HDIM * 2);
    size_t big_need = off;

    bool pathA = (ws_size >= big_need);

    if (pathA) {
        k_convert<<<2048, 256, 0, stream>>>(h, W, Wl, hb, Wbt, Wlbt, degi, meta, out, 0);
        k_hist<<<(N_EDGES + 255) / 256, 256, 0, stream>>>(rel, dst, meta, degi);
        k_scan_rel<<<1, 64, 0, stream>>>(meta);
        k_scatter<<<(N_EDGES + 255) / 256, 256, 0, stream>>>(rel, meta, sorted);
        k_bsum<<<NSCAN_BLK, 256, 0, stream>>>(degi, bsum);
        k_bscan<<<1, 64, 0, stream>>>(bsum, boff, seg);
        k_seg<<<NSCAN_BLK, 256, 0, stream>>>(degi, boff, seg, cursor);
        k_edgeA<<<MAX_TILES, 256, 0, stream>>>(hb, Wbt, src, dst, meta, sorted, cursor, msg);
        k_agg<<<(N_NODES + 3) / 4, 256, 0, stream>>>(msg, seg, aggB);
        k_selfA<<<(N_NODES + 63) / 64, 256, 0, stream>>>(hb, Wlbt, bias, aggB, out);
    } else {
        (void)small_need;
        k_convert<<<2048, 256, 0, stream>>>(h, W, Wl, hb, Wbt, Wlbt, degi, meta, out, 1);
        k_hist<<<(N_EDGES + 255) / 256, 256, 0, stream>>>(rel, dst, meta, degi);
        k_scan_rel<<<1, 64, 0, stream>>>(meta);
        k_scatter<<<(N_EDGES + 255) / 256, 256, 0, stream>>>(rel, meta, sorted);
        k_edgeB<<<MAX_TILES, 256, 0, stream>>>(hb, Wbt, src, dst, meta, sorted, out);
        k_selfB<<<(N_NODES + 63) / 64, 256, 0, stream>>>(hb, Wlbt, bias, degi, out);
    }
}